// Round 6
// baseline (171.347 us; speedup 1.0000x reference)
//
#include <hip/hip_runtime.h>
#include <math.h>

// Problem constants (fixed by reference)
#define N_   32
#define CIN  32
#define COUT 16
#define D_   16
#define S_   256            // W*H
#define M_   (CIN * S_)     // 8192
#define NBLK (N_ * CIN)     // 1024 blocks = exactly 4/CU x 256 CU co-resident

#define LOG2E 1.4426950408889634f

// MERGED accumulator row per (n,o): [0..15]=S (v-space), [16]=se, [17]=pad.
// 72 B, 8 B-aligned. Written ONLY by fire-and-forget global_atomic_add_f32
// from all 32 c-blocks; read (already merged) by 16 lanes per block.
#define AROW 18
#define AIDX(n, o) ((((size_t)(n) * COUT) + (o)) * AROW)

// Barrier layout: 3 passes x 32 n, each {count @ +0, flag @ +32} in a
// 64-int (256 B) slot -> counter and flag on different 128 B lines.
#define BSLOT 64

// Workspace float offsets: [bar: 6144 ints][ACC0][ACC1][ACC2] (9216 fl each)
#define WS_ACC0 6144
#define WS_ACC1 (6144 + 9216)
#define WS_ACC2 (6144 + 2 * 9216)

// ---- coherence-point (cache-bypass, sc1) primitives ----
// R3->R4 proved: RELAXED AGENT atomics + vmcnt-drained arrival ordering
// replace all __threadfence() L2 flushes. R5 lesson: sc1 LOAD COUNT is the
// cost metric (uncached, ~1-2k cy each) -> merge in memory via atomics so
// readers touch only the merged row.
__device__ __forceinline__ float2 aload_f2(const float* p) {
  unsigned long long v = __hip_atomic_load(
      (const unsigned long long*)p, __ATOMIC_RELAXED, __HIP_MEMORY_SCOPE_AGENT);
  float2 r;
  r.x = __uint_as_float((unsigned)v);
  r.y = __uint_as_float((unsigned)(v >> 32));
  return r;
}
__device__ __forceinline__ void afadd(float* p, float v) {
  (void)__hip_atomic_fetch_add(p, v, __ATOMIC_RELAXED,
                               __HIP_MEMORY_SCOPE_AGENT);
}

// LDS tile: ls[s][16 dd], 16B chunks XOR-swizzled; conflict-free b128 reads.
#define SW(s) ((((s) & 3)) ^ (((s) >> 2) & 3))

__device__ __forceinline__ void stage_tile(const float* __restrict__ gsrc,
                                           float* ls, int tid) {
  const float4* src = (const float4*)gsrc;
#pragma unroll
  for (int j = 0; j < 4; j++) {
    int f = ((tid & 3) << 6) + (tid >> 2) + (j << 8);  // float4 index in tile
    float4 val = src[f];
    int dd = f >> 6;
    int u  = f & 63;
    int chunk = dd >> 2, lo = dd & 3;
    float vv[4] = {val.x, val.y, val.z, val.w};
#pragma unroll
    for (int m = 0; m < 4; m++) {
      int s = (u << 2) + m;
      int p = chunk ^ SW(s);
      ls[(s << 4) + (p << 2) + lo] = vv[m];
    }
  }
}

__device__ __forceinline__ void read_lp(const float* ls, int s, float* lp) {
  const float4* row = (const float4*)(ls + (s << 4));
  int sw = SW(s);
#pragma unroll
  for (int c = 0; c < 4; c++) {
    float4 q = row[c ^ sw];
    lp[c * 4 + 0] = q.x; lp[c * 4 + 1] = q.y;
    lp[c * 4 + 2] = q.z; lp[c * 4 + 3] = q.w;
  }
}

// Split dot: 4 independent fma chains.
__device__ __forceinline__ float dot16(const float* a, const float* b) {
  float a0 = 0.f, a1 = 0.f, a2 = 0.f, a3 = 0.f;
#pragma unroll
  for (int k = 0; k < 4; k++) {
    a0 = fmaf(a[k],      b[k],      a0);
    a1 = fmaf(a[4 + k],  b[4 + k],  a1);
    a2 = fmaf(a[8 + k],  b[8 + k],  a2);
    a3 = fmaf(a[12 + k], b[12 + k], a3);
  }
  return (a0 + a1) + (a2 + a3);
}

// PER-N barrier, FENCE-FREE (R4, proven). The pre-arrival __syncthreads
// drains every wave's vmem ops (incl. the atomicAdd merges) to the
// coherence point before tid0's arrival add at the SAME point.
__device__ __forceinline__ void gbarrier(int* bar, int idx, int n, int tid) {
  __syncthreads();  // all block stores + atomics issued and vmcnt-drained
  if (tid == 0) {
    int* base = bar + ((idx << 5) + n) * BSLOT;
    if (__hip_atomic_fetch_add(base, 1, __ATOMIC_RELAXED,
                               __HIP_MEMORY_SCOPE_AGENT) == CIN - 1) {
      __hip_atomic_store(base + 32, 1, __ATOMIC_RELAXED,
                         __HIP_MEMORY_SCOPE_AGENT);
    } else {
      int guard = 0;
      while (__hip_atomic_load(base + 32, __ATOMIC_RELAXED,
                               __HIP_MEMORY_SCOPE_AGENT) == 0) {
        __builtin_amdgcn_s_sleep(2);  // ~128 cy between coherent-point reads
        if (++guard > 5000000) break;  // clean fail, no hang
      }
    }
  }
  __syncthreads();
}

// One routing sweep.
// PASS>0: 16 lanes load the MERGED row (9 sc1 loads each — was 2304/block),
//         squash, share dG + Dshift via hd. Dshift = log2(se_merged): shift
//         cancels exactly in a=e/se and in squash, so any per-(n,o)-
//         consistent overflow guard works; log2(se) bounds exp2 args by ~13.
// PASS==2: stream e to a_out (normal cached stores; re-read post-barrier by
//         the SAME block -> L1/L2 hit). Replaces the 4th recompute sweep.
// Store phase: 17 fire-and-forget float atomicAdds per lane into acc_out.
template <int PASS>
__device__ __forceinline__ void routing_pass(
    int n, int c, int tid, int o, int strip,
    const float* __restrict__ wgt,
    const float* __restrict__ acc_in, float* __restrict__ acc_out,
    float* __restrict__ a_out,
    const float* ls, float red[4][17][16], float red2[17][16],
    float hd[16][20], float* Gacc, float& shift) {
  if constexpr (PASS > 0) {
    if (tid < 16) {  // lane o=tid: read merged row, squash, share
      const float* r = acc_in + AIDX(n, tid);
      float H[16];
#pragma unroll
      for (int i = 0; i < 8; i++) {
        float2 v = aload_f2(r + 2 * i);
        H[2 * i + 0] = v.x;
        H[2 * i + 1] = v.y;
      }
      float se = aload_f2(r + 16).x;
      float inv = 1.0f / se, n2 = 0.f, Sg[16];
#pragma unroll
      for (int d = 0; d < 16; d++) { Sg[d] = H[d] * inv; n2 = fmaf(Sg[d], Sg[d], n2); }
      float coef = n2 / ((1.f + n2) * (sqrtf(n2) + 1e-6f));
      float4* hq = (float4*)hd[tid];
#pragma unroll
      for (int i = 0; i < 4; i++)
        hq[i] = make_float4(coef * Sg[i * 4 + 0], coef * Sg[i * 4 + 1],
                            coef * Sg[i * 4 + 2], coef * Sg[i * 4 + 3]);
      hd[tid][16] = __log2f(se);  // Dshift (se>0 always)
    }
    __syncthreads();  // hd ready
    // b is linear in accumulated g: Gacc += squash-head gives accumulated b.
    const float4* hq = (const float4*)hd[o];
#pragma unroll
    for (int i = 0; i < 4; i++) {
      float4 v = hq[i];
      Gacc[i * 4 + 0] += v.x; Gacc[i * 4 + 1] += v.y;
      Gacc[i * 4 + 2] += v.z; Gacc[i * 4 + 3] += v.w;
    }
    shift += hd[o][16];
  }

  // WG[i][j] = log2e * sum_k w[j][k] * G[i][k]  (wreg loaded, then dies)
  float WG[16];
  {
    float wreg[16];
    const float4* wp = (const float4*)(wgt + (c * COUT + o) * 16);
#pragma unroll
    for (int i = 0; i < 4; i++) {
      float4 t = wp[i];
      wreg[i * 4 + 0] = t.x; wreg[i * 4 + 1] = t.y;
      wreg[i * 4 + 2] = t.z; wreg[i * 4 + 3] = t.w;
    }
#pragma unroll
    for (int i = 0; i < 4; i++)
#pragma unroll
      for (int j = 0; j < 4; j++) {
        float acc = 0.f;
#pragma unroll
        for (int k = 0; k < 4; k++)
          acc = fmaf(wreg[j * 4 + k], Gacc[i * 4 + k], acc);
        WG[i * 4 + j] = acc * LOG2E;
      }
  }

  // ---- single-phase sweep: fixed shift, plain sums (unroll 4!) ----
  float se = 0.f, E[16];
#pragma unroll
  for (int d = 0; d < 16; d++) E[d] = 0.f;

  float* abase = a_out + ((size_t)(n * M_ + c * S_)) * COUT;

#pragma unroll 4
  for (int it = 0; it < 16; it++) {
    float lp[16];
    read_lp(ls, strip + (it << 4), lp);
    float b = dot16(lp, WG) - shift;
    float e = exp2f(b);
    if constexpr (PASS == 2) {
      abase[(size_t)((strip + (it << 4)) * COUT + o)] = e;  // stream e
    }
    se += e;
#pragma unroll
    for (int d = 0; d < 16; d++) E[d] = fmaf(e, lp[d], E[d]);
  }

  // within-wave merge over strip bits 4,5: plain adds
#pragma unroll
  for (int off = 16; off <= 32; off <<= 1) {
    se += __shfl_xor(se, off);
#pragma unroll
    for (int d = 0; d < 16; d++) E[d] += __shfl_xor(E[d], off);
  }

  const int w = tid >> 6;
  if ((tid & 63) < 16) {
#pragma unroll
    for (int d = 0; d < 16; d++) red[w][d][o] = E[d];
    red[w][16][o] = se;
  }
  __syncthreads();

  // cross-wave: plain 4-way sums
  for (int p = tid; p < 272; p += 256) {
    int f = p >> 4, oo = p & 15;
    red2[f][oo] = ((red[0][f][oo] + red[1][f][oo]) +
                   (red[2][f][oo] + red[3][f][oo]));
  }
  __syncthreads();

  if (tid < 16) {  // o = tid: E -> S (v-space), MERGE VIA ATOMICS
    float wt[16];
    const float4* wp = (const float4*)(wgt + (c * COUT + tid) * 16);
#pragma unroll
    for (int i = 0; i < 4; i++) {
      float4 t = wp[i];
      wt[i * 4 + 0] = t.x; wt[i * 4 + 1] = t.y;
      wt[i * 4 + 2] = t.z; wt[i * 4 + 3] = t.w;
    }
    float Et[16];
#pragma unroll
    for (int d = 0; d < 16; d++) Et[d] = red2[d][tid];
    float* pa = acc_out + AIDX(n, tid);
#pragma unroll
    for (int i = 0; i < 4; i++) {
      float s0 = 0.f, s1 = 0.f, s2 = 0.f, s3 = 0.f;
#pragma unroll
      for (int j = 0; j < 4; j++) {
        s0 = fmaf(Et[i * 4 + j], wt[j * 4 + 0], s0);
        s1 = fmaf(Et[i * 4 + j], wt[j * 4 + 1], s1);
        s2 = fmaf(Et[i * 4 + j], wt[j * 4 + 2], s2);
        s3 = fmaf(Et[i * 4 + j], wt[j * 4 + 3], s3);
      }
      afadd(pa + 4 * i + 0, s0); afadd(pa + 4 * i + 1, s1);
      afadd(pa + 4 * i + 2, s2); afadd(pa + 4 * i + 3, s3);
    }
    afadd(pa + 16, red2[16][tid]);
  }
}

// Fully fused, fence-free (R4 base, all R5 changes reverted). R6 changes:
//  1. Atomic-merge accumulators: per-pass partials are SUMMED AT THE
//     COHERENCE POINT by global_atomic_add_f32 (17/lane, fire-and-forget,
//     drained by the pre-barrier syncthreads). Head sc1-load count drops
//     2304 -> 144 per block; final drops 512 -> 16.
//  2. bmax tracking eliminated: shift += log2(se_merged) per pass (exactly
//     cancelling in a=e/se and squash; bounds exp2 args by ~13).
//  3. P2 streams e to a_out; final phase is a 16 KB L2-resident rescale
//     instead of a 4th full sweep.
__global__ __launch_bounds__(256, 4) void fused_kernel(
    const float* __restrict__ l, const float* __restrict__ wgt,
    const float* __restrict__ g0, float* __restrict__ a_out,
    float* __restrict__ g_out, float* __restrict__ acc0,
    float* __restrict__ acc1, float* __restrict__ acc2,
    int* __restrict__ bar) {
  const int bid = blockIdx.x;
  const int n = bid >> 5;
  const int c = bid & 31;
  const int tid = threadIdx.x;
  const int o = tid & 15;
  const int strip = tid >> 4;   // 16 s-strips

  __shared__ float ls[D_ * S_];        // 16 KB, staged once, read-only after
  __shared__ float red[4][17][16];     // 4.25 KB cross-wave buffer
  __shared__ float red2[17][16];       // 1.06 KB merged
  __shared__ float hd[16][20];         // 1.25 KB head share: dG[16], [16]=Dshift
  __shared__ float sinv[16];           // final 1/se per o

  stage_tile(l + ((size_t)(n * CIN + c)) * D_ * S_, ls, tid);

  float Gacc[16];
  {
    const float4* gp = (const float4*)(g0 + (n * COUT + o) * 16);
#pragma unroll
    for (int i = 0; i < 4; i++) {
      float4 u = gp[i];
      Gacc[i * 4 + 0] = u.x; Gacc[i * 4 + 1] = u.y;
      Gacc[i * 4 + 2] = u.z; Gacc[i * 4 + 3] = u.w;
    }
  }

  __syncthreads();  // tile staged

  float shift = 0.f;

  // P0: G = g0, shift 0, merge -> ACC0
  routing_pass<0>(n, c, tid, o, strip, wgt, nullptr, acc0, a_out, ls, red,
                  red2, hd, Gacc, shift);
  gbarrier(bar, 0, n, tid);
  // P1: Gacc += sq(ACC0), merge -> ACC1
  routing_pass<1>(n, c, tid, o, strip, wgt, acc0, acc1, a_out, ls, red,
                  red2, hd, Gacc, shift);
  gbarrier(bar, 1, n, tid);
  // P2: Gacc += sq(ACC1), merge -> ACC2, e streamed to a_out
  routing_pass<2>(n, c, tid, o, strip, wgt, acc1, acc2, a_out, ls, red,
                  red2, hd, Gacc, shift);
  gbarrier(bar, 2, n, tid);

  // ---- final: sinv from merged ACC2 (1 sc1 load/lane); c==0 emits g_out ----
  if (tid < 16) {
    const float* r = acc2 + AIDX(n, tid);
    float se = aload_f2(r + 16).x;
    float inv = 1.0f / se;
    sinv[tid] = inv;
    if (c == 0) {
      float Sv[16];
#pragma unroll
      for (int i = 0; i < 8; i++) {
        float2 v = aload_f2(r + 2 * i);
        Sv[2 * i + 0] = v.x;
        Sv[2 * i + 1] = v.y;
      }
      float n2 = 0.f;
#pragma unroll
      for (int d = 0; d < 16; d++) { Sv[d] *= inv; n2 = fmaf(Sv[d], Sv[d], n2); }
      float coef = n2 / ((1.f + n2) * (sqrtf(n2) + 1e-6f));
      float* go = g_out + (n * COUT + tid) * 16;
#pragma unroll
      for (int d = 0; d < 16; d++) go[d] = coef * Sv[d];
    }
  }
  __syncthreads();

  // a = e * sinv, in place over this block's own 16 KB chunk (L1/L2-hit:
  // written by this block in P2). Vectorized float4, coalesced.
  float4* pv = (float4*)(a_out + ((size_t)(n * M_ + c * S_)) * COUT);
#pragma unroll
  for (int r = 0; r < 4; r++) {
    int i4 = tid + (r << 8);
    int o0 = (i4 & 3) << 2;
    float4 v = pv[i4];
    v.x *= sinv[o0 + 0];
    v.y *= sinv[o0 + 1];
    v.z *= sinv[o0 + 2];
    v.w *= sinv[o0 + 3];
    pv[i4] = v;
  }
}

extern "C" void kernel_launch(void* const* d_in, const int* in_sizes, int n_in,
                              void* d_out, int out_size, void* d_ws, size_t ws_size,
                              hipStream_t stream) {
  const float* l = (const float*)d_in[0];
  const float* g = (const float*)d_in[1];
  const float* w = (const float*)d_in[2];
  // d_in[3] = num_iters (always 3 per setup_inputs)

  float* out = (float*)d_out;
  float* a_out = out;
  float* g_out = out + (size_t)N_ * M_ * COUT;

  float* ws = (float*)d_ws;
  int* bar = (int*)ws;                 // 3x32 slots, 24 KB
  float* acc0 = ws + WS_ACC0;          // 36 KB each, atomic-merged rows
  float* acc1 = ws + WS_ACC1;
  float* acc2 = ws + WS_ACC2;

  // Zero barriers + all three accumulator buffers in one contiguous memset
  // (ws is re-poisoned between runs). 24576 + 3*36864 = 135168 B.
  hipMemsetAsync(ws, 0, 135168, stream);

  fused_kernel<<<NBLK, 256, 0, stream>>>(l, w, g, a_out, g_out, acc0, acc1,
                                         acc2, bar);
}

// Round 7
// 133.582 us; speedup vs baseline: 1.2827x; 1.2827x over previous
//
#include <hip/hip_runtime.h>
#include <math.h>

// Problem constants (fixed by reference)
#define N_   32
#define CIN  32
#define COUT 16
#define D_   16
#define S_   256            // W*H
#define M_   (CIN * S_)     // 8192
#define NBLK (N_ * CIN)     // 1024 blocks = exactly 4/CU x 256 CU co-resident

#define LOG2E 1.4426950408889634f

// PRIVATE partial row per (n,c,o): [0..15]=S (v-space), [16]=se, [17]=pad.
// 80 B rows, 8 B-aligned; written by ONE block only (no atomic contention,
// R6 lesson), read by ONE leader block only (no redundancy, R4/R5 lesson).
#define PROW 20
#define PIDX(n, c, o) ((((size_t)(n) * CIN + (c)) * COUT + (o)) * PROW)

// Published head row per (n,o): [0..15]=dG, [16]=Dshift (or [0]=sinv, final).
#define PUBROW 20
#define PUBIDX(n, o) ((((size_t)(n) * COUT) + (o)) * PUBROW)

// Barrier: 3 passes x 32 n, {count @ +0, flag @ +32} in a 64-int slot.
#define BSLOT 64

// Workspace float offsets: [bar 6144 ints][PB 327680][PUB 10240]
#define WS_PB  6144
#define WS_PUB (6144 + 327680)

// ---- coherence-point (cache-bypass, sc1) primitives (R4-proven) ----
__device__ __forceinline__ float2 aload_f2(const float* p) {
  unsigned long long v = __hip_atomic_load(
      (const unsigned long long*)p, __ATOMIC_RELAXED, __HIP_MEMORY_SCOPE_AGENT);
  float2 r;
  r.x = __uint_as_float((unsigned)v);
  r.y = __uint_as_float((unsigned)(v >> 32));
  return r;
}
__device__ __forceinline__ void astore_f2(float* p, float a, float b) {
  unsigned long long v =
      ((unsigned long long)__float_as_uint(b) << 32) | __float_as_uint(a);
  __hip_atomic_store((unsigned long long*)p, v, __ATOMIC_RELAXED,
                     __HIP_MEMORY_SCOPE_AGENT);
}

// LDS tile: ls[s][16 dd], 16B chunks XOR-swizzled; conflict-free b128 reads.
#define SW(s) ((((s) & 3)) ^ (((s) >> 2) & 3))

__device__ __forceinline__ void stage_tile(const float* __restrict__ gsrc,
                                           float* ls, int tid) {
  const float4* src = (const float4*)gsrc;
#pragma unroll
  for (int j = 0; j < 4; j++) {
    int f = ((tid & 3) << 6) + (tid >> 2) + (j << 8);  // float4 index in tile
    float4 val = src[f];
    int dd = f >> 6;
    int u  = f & 63;
    int chunk = dd >> 2, lo = dd & 3;
    float vv[4] = {val.x, val.y, val.z, val.w};
#pragma unroll
    for (int m = 0; m < 4; m++) {
      int s = (u << 2) + m;
      int p = chunk ^ SW(s);
      ls[(s << 4) + (p << 2) + lo] = vv[m];
    }
  }
}

__device__ __forceinline__ void read_lp(const float* ls, int s, float* lp) {
  const float4* row = (const float4*)(ls + (s << 4));
  int sw = SW(s);
#pragma unroll
  for (int c = 0; c < 4; c++) {
    float4 q = row[c ^ sw];
    lp[c * 4 + 0] = q.x; lp[c * 4 + 1] = q.y;
    lp[c * 4 + 2] = q.z; lp[c * 4 + 3] = q.w;
  }
}

// Split dot: 4 independent fma chains.
__device__ __forceinline__ float dot16(const float* a, const float* b) {
  float a0 = 0.f, a1 = 0.f, a2 = 0.f, a3 = 0.f;
#pragma unroll
  for (int k = 0; k < 4; k++) {
    a0 = fmaf(a[k],      b[k],      a0);
    a1 = fmaf(a[4 + k],  b[4 + k],  a1);
    a2 = fmaf(a[8 + k],  b[8 + k],  a2);
    a3 = fmaf(a[12 + k], b[12 + k], a3);
  }
  return (a0 + a1) + (a2 + a3);
}

__device__ __forceinline__ void build_WG(const float* __restrict__ wgt, int c,
                                         int o, const float* Gacc, float* WG) {
  float wreg[16];
  const float4* wp = (const float4*)(wgt + (c * COUT + o) * 16);
#pragma unroll
  for (int i = 0; i < 4; i++) {
    float4 t = wp[i];
    wreg[i * 4 + 0] = t.x; wreg[i * 4 + 1] = t.y;
    wreg[i * 4 + 2] = t.z; wreg[i * 4 + 3] = t.w;
  }
#pragma unroll
  for (int i = 0; i < 4; i++)
#pragma unroll
    for (int j = 0; j < 4; j++) {
      float acc = 0.f;
#pragma unroll
      for (int k = 0; k < 4; k++)
        acc = fmaf(wreg[j * 4 + k], Gacc[i * 4 + k], acc);
      WG[i * 4 + j] = acc * LOG2E;
    }
}

// One sweep + block-reduce + PRIVATE partial-row store (sc1, contention-free).
__device__ __forceinline__ void sweep_store(
    int n, int c, int tid, int o, int strip,
    const float* __restrict__ wgt, float* __restrict__ PB,
    const float* ls, float red[4][17][16], float red2[17][16],
    const float* Gacc, float shift) {
  float WG[16];
  build_WG(wgt, c, o, Gacc, WG);

  float se = 0.f, E[16];
#pragma unroll
  for (int d = 0; d < 16; d++) E[d] = 0.f;

#pragma unroll 4
  for (int it = 0; it < 16; it++) {
    float lp[16];
    read_lp(ls, strip + (it << 4), lp);
    float e = exp2f(dot16(lp, WG) - shift);
    se += e;
#pragma unroll
    for (int d = 0; d < 16; d++) E[d] = fmaf(e, lp[d], E[d]);
  }

  // within-wave merge over strip bits 4,5
#pragma unroll
  for (int off = 16; off <= 32; off <<= 1) {
    se += __shfl_xor(se, off);
#pragma unroll
    for (int d = 0; d < 16; d++) E[d] += __shfl_xor(E[d], off);
  }

  const int w = tid >> 6;
  if ((tid & 63) < 16) {
#pragma unroll
    for (int d = 0; d < 16; d++) red[w][d][o] = E[d];
    red[w][16][o] = se;
  }
  __syncthreads();

  for (int p = tid; p < 272; p += 256) {
    int f = p >> 4, oo = p & 15;
    red2[f][oo] = ((red[0][f][oo] + red[1][f][oo]) +
                   (red[2][f][oo] + red[3][f][oo]));
  }
  __syncthreads();

  if (tid < 16) {  // o = tid: E -> S (v-space), private sc1 store
    float wt[16];
    const float4* wp = (const float4*)(wgt + (c * COUT + tid) * 16);
#pragma unroll
    for (int i = 0; i < 4; i++) {
      float4 t = wp[i];
      wt[i * 4 + 0] = t.x; wt[i * 4 + 1] = t.y;
      wt[i * 4 + 2] = t.z; wt[i * 4 + 3] = t.w;
    }
    float Et[16];
#pragma unroll
    for (int d = 0; d < 16; d++) Et[d] = red2[d][tid];
    float* p0 = PB + PIDX(n, c, tid);
#pragma unroll
    for (int i = 0; i < 4; i++) {
      float s0 = 0.f, s1 = 0.f, s2 = 0.f, s3 = 0.f;
#pragma unroll
      for (int j = 0; j < 4; j++) {
        s0 = fmaf(Et[i * 4 + j], wt[j * 4 + 0], s0);
        s1 = fmaf(Et[i * 4 + j], wt[j * 4 + 1], s1);
        s2 = fmaf(Et[i * 4 + j], wt[j * 4 + 2], s2);
        s3 = fmaf(Et[i * 4 + j], wt[j * 4 + 3], s3);
      }
      astore_f2(p0 + 4 * i + 0, s0, s1);
      astore_f2(p0 + 4 * i + 2, s2, s3);
    }
    astore_f2(p0 + 16, red2[16][tid], 0.f);
  }
}

// LEADER-BASED exchange (R7). The LAST arriver at the per-n barrier merges
// the group's 32 private rows with all 256 threads (18 sc1 loads each),
// squashes once, publishes dG+Dshift (1.1 KB), then releases the flag.
// Others spin, then read only the 1.1 KB published head. Head sc1 traffic
// drops 32x vs R4 (1.15 MB -> 36 KB per n-group per pass); zero atomic
// contention (R6 lesson). Leadership is block-uniform -> divergent barriers
// are safe. FINAL: leader publishes sinv + writes g_out.
template <int SLOT, bool FINAL>
__device__ __forceinline__ void exchange(
    int n, int tid, const float* __restrict__ PB, float* __restrict__ pub,
    float* __restrict__ g_out, int* __restrict__ bar,
    float red[4][17][16], float hd[16][20], float* sinv, int* lead) {
  __syncthreads();  // drain this block's private-row sc1 stores (all waves)
  if (tid == 0) {
    int* base = bar + ((SLOT << 5) + n) * BSLOT;
    *lead = (__hip_atomic_fetch_add(base, 1, __ATOMIC_RELAXED,
                                    __HIP_MEMORY_SCOPE_AGENT) == CIN - 1);
  }
  __syncthreads();

  if (*lead) {
    // ---- 256-thread merge: wave w, lane(hs=0..3, ho=0..15), c=hs+4*(2w+j)
    const int l = tid & 63, w = tid >> 6;
    const int ho = l & 15, hs = l >> 4;
    float H[17];
#pragma unroll
    for (int f = 0; f < 17; f++) H[f] = 0.f;
#pragma unroll
    for (int j = 0; j < 2; j++) {
      const float* r = PB + PIDX(n, hs + 4 * (2 * w + j), ho);
#pragma unroll
      for (int i = 0; i < 8; i++) {
        float2 v = aload_f2(r + 2 * i);
        H[2 * i + 0] += v.x;
        H[2 * i + 1] += v.y;
      }
      H[16] += aload_f2(r + 16).x;
    }
#pragma unroll
    for (int off = 16; off <= 32; off <<= 1)
#pragma unroll
      for (int f = 0; f < 17; f++) H[f] += __shfl_xor(H[f], off);
    if (l < 16) {
#pragma unroll
      for (int f = 0; f < 17; f++) red[w][f][ho] = H[f];
    }
    __syncthreads();
    if (tid < 16) {
      float S[16], se;
#pragma unroll
      for (int f = 0; f < 16; f++)
        S[f] = (red[0][f][tid] + red[1][f][tid]) +
               (red[2][f][tid] + red[3][f][tid]);
      se = (red[0][16][tid] + red[1][16][tid]) +
           (red[2][16][tid] + red[3][16][tid]);
      float inv = 1.0f / se;
      if (FINAL) {
        sinv[tid] = inv;
        __hip_atomic_store(pub + PUBIDX(n, tid), inv, __ATOMIC_RELAXED,
                           __HIP_MEMORY_SCOPE_AGENT);
        float n2 = 0.f, Sg[16];
#pragma unroll
        for (int d = 0; d < 16; d++) { Sg[d] = S[d] * inv; n2 = fmaf(Sg[d], Sg[d], n2); }
        float coef = n2 / ((1.f + n2) * (sqrtf(n2) + 1e-6f));
        float* go = g_out + (n * COUT + tid) * 16;
#pragma unroll
        for (int d = 0; d < 16; d++) go[d] = coef * Sg[d];
      } else {
        float n2 = 0.f, Sg[16];
#pragma unroll
        for (int d = 0; d < 16; d++) { Sg[d] = S[d] * inv; n2 = fmaf(Sg[d], Sg[d], n2); }
        float coef = n2 / ((1.f + n2) * (sqrtf(n2) + 1e-6f));
        float Dsh = __log2f(se);  // se > 0 always
        float* hrow = hd[tid];
        float* prow = pub + PUBIDX(n, tid);
#pragma unroll
        for (int i = 0; i < 8; i++) {
          float a = coef * Sg[2 * i], b = coef * Sg[2 * i + 1];
          hrow[2 * i] = a; hrow[2 * i + 1] = b;
          astore_f2(prow + 2 * i, a, b);
        }
        hrow[16] = Dsh;
        astore_f2(prow + 16, Dsh, 0.f);
      }
    }
    __syncthreads();  // publish stores vmcnt-drained; hd/sinv visible in LDS
    if (tid == 0) {
      int* base = bar + ((SLOT << 5) + n) * BSLOT;
      __hip_atomic_store(base + 32, 1, __ATOMIC_RELAXED,
                         __HIP_MEMORY_SCOPE_AGENT);
    }
  } else {
    if (tid == 0) {
      int* base = bar + ((SLOT << 5) + n) * BSLOT;
      int guard = 0;
      while (__hip_atomic_load(base + 32, __ATOMIC_RELAXED,
                               __HIP_MEMORY_SCOPE_AGENT) == 0) {
        __builtin_amdgcn_s_sleep(2);
        if (++guard > 5000000) break;  // clean fail, no hang
      }
    }
    __syncthreads();  // all threads gated on flag
    if (FINAL) {
      if (tid < 16)
        sinv[tid] = __hip_atomic_load(pub + PUBIDX(n, tid), __ATOMIC_RELAXED,
                                      __HIP_MEMORY_SCOPE_AGENT);
    } else {
      if (tid < 16) {
        const float* prow = pub + PUBIDX(n, tid);
        float* hrow = hd[tid];
#pragma unroll
        for (int i = 0; i < 8; i++) {
          float2 v = aload_f2(prow + 2 * i);
          hrow[2 * i] = v.x; hrow[2 * i + 1] = v.y;
        }
        hrow[16] = aload_f2(prow + 16).x;
      }
    }
    __syncthreads();  // hd/sinv ready
  }
}

// Fully fused, fence-free, leader-exchange (R7). Changes vs R4 (62 us):
//  - heads computed ONCE per n-group by the last-arriving block (32x less
//    sc1 read traffic), broadcast via 1.1 KB publish rows
//  - single PB buffer reused across passes (leader finishes reading before
//    releasing the flag; next-pass stores happen only after the flag)
//  - bmax dropped: shift += log2(se_merged) (R6-validated, cancels exactly)
//  - e-streaming reverted (R6's +13 MB HBM writes); final recompute sweep.
__global__ __launch_bounds__(256, 4) void fused_kernel(
    const float* __restrict__ l, const float* __restrict__ wgt,
    const float* __restrict__ g0, float* __restrict__ a_out,
    float* __restrict__ g_out, float* __restrict__ PB,
    float* __restrict__ pub, int* __restrict__ bar) {
  const int bid = blockIdx.x;
  const int n = bid >> 5;
  const int c = bid & 31;
  const int tid = threadIdx.x;
  const int o = tid & 15;
  const int strip = tid >> 4;   // 16 s-strips

  __shared__ float ls[D_ * S_];        // 16 KB, staged once, read-only after
  __shared__ float red[4][17][16];     // 4.25 KB cross-wave buffer
  __shared__ float red2[17][16];       // 1.06 KB merged
  __shared__ float hd[16][20];         // 1.25 KB head: dG[16], [16]=Dshift
  __shared__ float sinv[16];           // final 1/se per o
  __shared__ int lead;                 // block-uniform leadership flag

  stage_tile(l + ((size_t)(n * CIN + c)) * D_ * S_, ls, tid);

  float Gacc[16];
  {
    const float4* gp = (const float4*)(g0 + (n * COUT + o) * 16);
#pragma unroll
    for (int i = 0; i < 4; i++) {
      float4 u = gp[i];
      Gacc[i * 4 + 0] = u.x; Gacc[i * 4 + 1] = u.y;
      Gacc[i * 4 + 2] = u.z; Gacc[i * 4 + 3] = u.w;
    }
  }

  __syncthreads();  // tile staged

  float shift = 0.f;

  // P0: G = g0, shift 0 -> PB; exchange -> hd
  sweep_store(n, c, tid, o, strip, wgt, PB, ls, red, red2, Gacc, shift);
  exchange<0, false>(n, tid, PB, pub, g_out, bar, red, hd, sinv, &lead);
  {
    const float4* hq = (const float4*)hd[o];
#pragma unroll
    for (int i = 0; i < 4; i++) {
      float4 v = hq[i];
      Gacc[i * 4 + 0] += v.x; Gacc[i * 4 + 1] += v.y;
      Gacc[i * 4 + 2] += v.z; Gacc[i * 4 + 3] += v.w;
    }
    shift += hd[o][16];
  }

  // P1
  sweep_store(n, c, tid, o, strip, wgt, PB, ls, red, red2, Gacc, shift);
  exchange<1, false>(n, tid, PB, pub, g_out, bar, red, hd, sinv, &lead);
  {
    const float4* hq = (const float4*)hd[o];
#pragma unroll
    for (int i = 0; i < 4; i++) {
      float4 v = hq[i];
      Gacc[i * 4 + 0] += v.x; Gacc[i * 4 + 1] += v.y;
      Gacc[i * 4 + 2] += v.z; Gacc[i * 4 + 3] += v.w;
    }
    shift += hd[o][16];
  }

  // P2 (Gacc/shift now final; used again by the a-recompute below)
  sweep_store(n, c, tid, o, strip, wgt, PB, ls, red, red2, Gacc, shift);
  exchange<2, true>(n, tid, PB, pub, g_out, bar, red, hd, sinv, &lead);

  // ---- a = exp2(dot(lp,WG)-shift) * sinv — recomputed bitwise-identically
  // to P2's sweep (same ls reads, same WG from same Gacc, same op order).
  // Stores coalesce: per it, one contiguous 1 KB span per block.
  float WG[16];
  build_WG(wgt, c, o, Gacc, WG);
  const float myinv = sinv[o];
  float* abase = a_out + ((size_t)(n * M_ + c * S_)) * COUT;
#pragma unroll 4
  for (int it = 0; it < 16; it++) {
    float lp[16];
    read_lp(ls, strip + (it << 4), lp);
    float b = dot16(lp, WG) - shift;
    abase[(size_t)((strip + (it << 4)) * COUT + o)] = exp2f(b) * myinv;
  }
}

extern "C" void kernel_launch(void* const* d_in, const int* in_sizes, int n_in,
                              void* d_out, int out_size, void* d_ws, size_t ws_size,
                              hipStream_t stream) {
  const float* l = (const float*)d_in[0];
  const float* g = (const float*)d_in[1];
  const float* w = (const float*)d_in[2];
  // d_in[3] = num_iters (always 3 per setup_inputs)

  float* out = (float*)d_out;
  float* a_out = out;
  float* g_out = out + (size_t)N_ * M_ * COUT;

  float* ws = (float*)d_ws;
  int* bar = (int*)ws;                 // 3x32 slots, 24 KB (memset below)
  float* PB = ws + WS_PB;              // 1.31 MB private partial rows
  float* pub = ws + WS_PUB;            // 40 KB publish rows

  // Zero only the barrier slots (PB/pub are fully written before read).
  hipMemsetAsync(bar, 0, 3 * N_ * BSLOT * sizeof(int), stream);

  fused_kernel<<<NBLK, 256, 0, stream>>>(l, w, g, a_out, g_out, PB, pub, bar);
}